// Round 4
// baseline (362.301 us; speedup 1.0000x reference)
//
#include <hip/hip_runtime.h>
#include <hip/hip_bf16.h>

#define M_ROWS 16384
#define D_DIM  1024
#define K_CB   4096

#define MTILE  128               // z rows per block
#define NTILE  128               // cb cols per chunk
#define BK     32
#define KSTEPS (D_DIM / BK)                // 32
#define MBLOCKS (M_ROWS / MTILE)           // 128

typedef __attribute__((ext_vector_type(8))) short short8;
typedef __attribute__((ext_vector_type(4))) float f32x4;

static __device__ __forceinline__ unsigned short f2bf(float f) {
  unsigned u = __float_as_uint(f);
  unsigned r = ((u >> 16) & 1u) + 0x7FFFu;   // RNE
  return (unsigned short)((u + r) >> 16);
}

// monotone float->u32 key (all finite floats ordered)
static __device__ __forceinline__ unsigned f2sortable(float f) {
  unsigned u = __float_as_uint(f);
  return (u & 0x80000000u) ? ~u : (u | 0x80000000u);
}

static __device__ __forceinline__ float sortable2f(unsigned s) {
  unsigned u = (s & 0x80000000u) ? (s ^ 0x80000000u) : ~s;
  return __uint_as_float(u);
}

static __device__ __forceinline__ void gload_lds16(const unsigned short* g, unsigned short* l) {
  __builtin_amdgcn_global_load_lds(
      (const __attribute__((address_space(1))) void*)g,
      (__attribute__((address_space(3))) void*)l, 16, 0, 0);
}

// ---------------- Kernel 1: l2-normalize rows -> bf16 ----------------
__global__ __launch_bounds__(256)
void k_normalize(const float* __restrict__ z, const float* __restrict__ cb,
                 unsigned short* __restrict__ zf, unsigned short* __restrict__ cbf) {
  const int bid = blockIdx.x;
  const float* src;
  unsigned short* dst;
  if (bid < M_ROWS) {
    src = z + (size_t)bid * D_DIM;
    dst = zf + (size_t)bid * D_DIM;
  } else {
    const int r = bid - M_ROWS;
    src = cb + (size_t)r * D_DIM;
    dst = cbf + (size_t)r * D_DIM;
  }
  const int t = threadIdx.x;
  const float4 v = ((const float4*)src)[t];
  float ss = v.x * v.x + v.y * v.y + v.z * v.z + v.w * v.w;
#pragma unroll
  for (int off = 32; off > 0; off >>= 1) ss += __shfl_down(ss, off, 64);
  __shared__ float sp[4];
  if ((t & 63) == 0) sp[t >> 6] = ss;
  __syncthreads();
  const float tot = sp[0] + sp[1] + sp[2] + sp[3];
  const float invn = 1.0f / sqrtf(tot + 1e-12f);
  ushort4 o;
  o.x = f2bf(v.x * invn);
  o.y = f2bf(v.y * invn);
  o.z = f2bf(v.z * invn);
  o.w = f2bf(v.w * invn);
  ((ushort4*)dst)[t] = o;
}

// ---------------- Kernel 2: fused bf16 GEMM (swapped) + register top-8 ----------------
// D = Cf_tile (128 cb) x Zf_tile^T (128 z): D-row = cb col, D-col = z row.
// Lane (per nj): one z row, 16 cb values (4 mi x 4 regs) -> lane-local top-8.
// LDS swizzle: slot s' = s ^ ((row>>1)&3). Bank-quad q=(4r+s') mod 8 walks
// {0,4,1,5,2,6,3,7} over rows 0..7 -> 16-row fragment read = 2-way (free).
// (Round-3 bug: s^(r&3) gave q-period 4 -> 4-way conflict, 1.77e7 cycles.)
template<int NS>
__global__ __launch_bounds__(256, 2)
void k_gemm_topk(const unsigned short* __restrict__ zf,
                 const unsigned short* __restrict__ cbf,
                 unsigned* __restrict__ part) {
  constexpr int COLS_PER_SPLIT = K_CB / NS;
  constexpr int CHUNKS = COLS_PER_SPLIT / NTILE;
  constexpr int GITERS = CHUNKS * KSTEPS;

  __shared__ unsigned short smem[4][MTILE * BK];  // [0..1]=Z dbuf, [2..3]=C dbuf (32 KB)

  const int tid  = threadIdx.x;
  const int lane = tid & 63;
  const int wid  = tid >> 6;
  const int wc   = wid & 1;    // cb-dir wave (2)
  const int wz   = wid >> 1;   // z-dir wave (2)
  const int lo   = lane & 15;
  const int hi   = lane >> 4;

  // XCD-aware remap (xcd = wgid&7 round-robin assumption).
  // NS=8: each XCD owns one 1MB codebook slab. NS=4: 2 XCDs per slab.
  const int wgid  = blockIdx.x + (int)gridDim.x * blockIdx.y;
  const int xcd   = wgid & 7;
  int split, mtile;
  if (NS == 8) { split = xcd;      mtile = wgid >> 3; }
  else         { split = xcd >> 1; mtile = ((wgid >> 3) << 1) + (xcd & 1); }
  const int rbase = mtile * MTILE;
  const int cbase = split * COLS_PER_SPLIT;

  // fragment LDS element offsets (row/col = lo, k-chunk = hi, swizzled slot)
  int coff[4], zoff[4];
#pragma unroll
  for (int mi = 0; mi < 4; ++mi) {
    const int r = wc * 64 + mi * 16 + lo;
    coff[mi] = r * BK + ((hi ^ ((r >> 1) & 3)) << 3);
  }
#pragma unroll
  for (int nj = 0; nj < 4; ++nj) {
    const int r = wz * 64 + nj * 16 + lo;
    zoff[nj] = r * BK + ((hi ^ ((r >> 1) & 3)) << 3);
  }

  // staging: thread tid -> LDS 16B slot tid (row tid>>2, kslot tid&3), linear dest;
  // global source pre-swizzled with the same involution.
  const int srow = tid >> 2;
  const int ksrc = ((tid & 3) ^ ((srow >> 1) & 3)) << 3;
  const long srcZ = (long)(rbase + srow) * D_DIM + ksrc;
  const long srcC = (long)(cbase + srow) * D_DIM + ksrc;

  f32x4 acc[4][4];
#pragma unroll
  for (int mi = 0; mi < 4; ++mi)
#pragma unroll
    for (int nj = 0; nj < 4; ++nj) acc[mi][nj] = (f32x4){0.f, 0.f, 0.f, 0.f};

  unsigned tk[4][8];
  unsigned tkmin[4];
  float    tminf[4];
#pragma unroll
  for (int l = 0; l < 4; ++l) {
    tkmin[l] = 0u;
    tminf[l] = -__builtin_inff();
#pragma unroll
    for (int q = 0; q < 8; ++q) tk[l][q] = 0u;
  }

  auto STAGE = [&](int g1) {
    const int b = g1 & 1;
    const long kb = (long)((g1 & (KSTEPS - 1)) << 5);
    const long cc = (long)(g1 >> 5) * (NTILE * D_DIM);
    gload_lds16(zf + srcZ + kb,                 &smem[b][tid * 8]);
    gload_lds16(zf + srcZ + 64 * D_DIM + kb,    &smem[b][2048 + tid * 8]);
    gload_lds16(cbf + srcC + cc + kb,           &smem[2 + b][tid * 8]);
    gload_lds16(cbf + srcC + cc + 64 * D_DIM + kb, &smem[2 + b][2048 + tid * 8]);
  };

  auto COMPUTE = [&](int b) {
    const unsigned short* Z = smem[b];
    const unsigned short* C = smem[2 + b];
    short8 cf[4], zr[4];
#pragma unroll
    for (int mi = 0; mi < 4; ++mi) cf[mi] = *(const short8*)(C + coff[mi]);
#pragma unroll
    for (int nj = 0; nj < 4; ++nj) zr[nj] = *(const short8*)(Z + zoff[nj]);
#pragma unroll
    for (int mi = 0; mi < 4; ++mi)
#pragma unroll
      for (int nj = 0; nj < 4; ++nj)
        acc[mi][nj] = __builtin_amdgcn_mfma_f32_16x16x32_bf16(cf[mi], zr[nj], acc[mi][nj], 0, 0, 0);
  };

  STAGE(0);
  __syncthreads();

  for (int g = 0; g < GITERS; ++g) {
    if (g + 1 < GITERS) STAGE(g + 1);
    COMPUTE(g & 1);
    __syncthreads();

    if ((g & (KSTEPS - 1)) == (KSTEPS - 1)) {          // chunk complete: register top-k
      const int cfb = cbase + (g >> 5) * NTILE + wc * 64 + hi * 4;
#pragma unroll
      for (int nj = 0; nj < 4; ++nj) {
#pragma unroll
        for (int mi = 0; mi < 4; ++mi) {
#pragma unroll
          for (int r = 0; r < 4; ++r) {
            const float v = acc[mi][nj][r];
            // must be !(v <= t): while table has empty slots tminf is NaN ->
            // falls through to the exact u32 check. (v > NaN) starves (round-2 bug).
            if (!(v <= tminf[nj])) {
              const unsigned key = (f2sortable(v) & ~0xFFFu) | (unsigned)(cfb + mi * 16 + r);
              if (key > tkmin[nj]) {
                int ms = 0;
                unsigned mv = tk[nj][0];
#pragma unroll
                for (int q = 1; q < 8; ++q) { if (tk[nj][q] < mv) { mv = tk[nj][q]; ms = q; } }
#pragma unroll
                for (int q = 0; q < 8; ++q) tk[nj][q] = (q == ms) ? key : tk[nj][q];
                mv = tk[nj][0];
#pragma unroll
                for (int q = 1; q < 8; ++q) mv = (tk[nj][q] < mv) ? tk[nj][q] : mv;
                tkmin[nj] = mv;
                tminf[nj] = sortable2f(mv & ~0xFFFu);
              }
            }
            acc[mi][nj][r] = 0.f;
          }
        }
      }
    }
  }

  // final merge: per z row, 8 lanes x 8 keys -> LDS (aliases smem), then top-8 scan
  __syncthreads();
  unsigned* mrg = (unsigned*)smem;   // [128][64]
  {
    const int slot = wc * 4 + hi;
#pragma unroll
    for (int nj = 0; nj < 4; ++nj) {
      const int zrow = wz * 64 + nj * 16 + lo;
#pragma unroll
      for (int q = 0; q < 8; ++q) mrg[zrow * 64 + slot * 8 + q] = tk[nj][q];
    }
  }
  __syncthreads();
  if (tid < MTILE) {
    const unsigned* c = mrg + tid * 64;
    unsigned top[8];
#pragma unroll
    for (int p = 0; p < 8; ++p) top[p] = 0u;
    unsigned tmin = 0u;
    for (int q0 = 0; q0 < 64; ++q0) {
      const unsigned k = c[(q0 + tid) & 63];   // rotate to avoid bank conflicts
      if (k > tmin) {
        int ms = 0;
        unsigned mv = top[0];
#pragma unroll
        for (int q = 1; q < 8; ++q) { if (top[q] < mv) { mv = top[q]; ms = q; } }
#pragma unroll
        for (int q = 0; q < 8; ++q) top[q] = (q == ms) ? k : top[q];
        mv = top[0];
#pragma unroll
        for (int q = 1; q < 8; ++q) mv = (top[q] < mv) ? top[q] : mv;
        tmin = mv;
      }
    }
    unsigned* dst = part + ((size_t)(rbase + tid) * NS + split) * 8;
#pragma unroll
    for (int p = 0; p < 8; ++p) dst[p] = top[p];
  }
}

// ---------------- Kernel 3: merge splits, softmax, gather E, gate ----------------
template<int NS>
__global__ __launch_bounds__(256)
void k_gate(const unsigned* __restrict__ part, const float* __restrict__ target,
            const float* __restrict__ E, float* __restrict__ out) {
  constexpr int NK = NS * 8;       // 32 or 64 candidate keys per row
  const int row = blockIdx.x;
  const int t = threadIdx.x;
  __shared__ float s_alpha[8];
  __shared__ int s_idx[8];
  __shared__ unsigned s_key[8];

  if (t < NK) {
    unsigned k = part[(size_t)row * NK + t];
#pragma unroll
    for (int p = 0; p < 8; ++p) {
      unsigned m = k;
#pragma unroll
      for (int off = NK / 2; off > 0; off >>= 1) {
        const unsigned o = __shfl_xor(m, off, NK);
        m = (m > o) ? m : o;
      }
      if (k == m) { s_key[p] = k; k = 0u; }  // keys distinct (idx in low bits)
    }
  }
  __syncthreads();
  if (t < 8) {
    const unsigned key = s_key[t];
    const float val  = 10.0f * sortable2f(key & ~0xFFFu);
    const float vmax = 10.0f * sortable2f(s_key[0] & ~0xFFFu);
    const float e = expf(val - vmax);
    float s = e;
#pragma unroll
    for (int off = 4; off > 0; off >>= 1) s += __shfl_xor(s, off, 8);
    s_alpha[t] = e / s;
    s_idx[t] = (int)(key & 0xFFFu);
  }
  __syncthreads();

  float4 g = {0.f, 0.f, 0.f, 0.f};
#pragma unroll
  for (int p = 0; p < 8; ++p) {
    const float a = s_alpha[p];
    const float4 e4 = ((const float4*)E)[(size_t)s_idx[p] * 256 + t];
    g.x += a * e4.x;
    g.y += a * e4.y;
    g.z += a * e4.z;
    g.w += a * e4.w;
  }
  const float4 tg = ((const float4*)target)[(size_t)row * 256 + t];
  float4 o;
  o.x = tg.x * (1.f + g.x);
  o.y = tg.y * (1.f + g.y);
  o.z = tg.z * (1.f + g.z);
  o.w = tg.w * (1.f + g.w);
  ((float4*)out)[(size_t)row * 256 + t] = o;
}

extern "C" void kernel_launch(void* const* d_in, const int* in_sizes, int n_in,
                              void* d_out, int out_size, void* d_ws, size_t ws_size,
                              hipStream_t stream) {
  const float* z      = (const float*)d_in[0];
  const float* target = (const float*)d_in[1];
  const float* cb     = (const float*)d_in[2];
  const float* E      = (const float*)d_in[3];
  float* out = (float*)d_out;

  // d_out doubles as scratch for the bf16 normalized matrices (dead before k_gate writes)
  unsigned short* zf  = (unsigned short*)d_out;                       // 32 MB
  unsigned short* cbf = (unsigned short*)((char*)d_out + 33554432);   // 8 MB @ +32MB
  unsigned* part = (unsigned*)d_ws;

  k_normalize<<<dim3(M_ROWS + K_CB), dim3(256), 0, stream>>>(z, cb, zf, cbf);

  const size_t need8 = (size_t)M_ROWS * 8 * 8 * sizeof(unsigned);     // 4 MB
  if (ws_size >= need8) {
    k_gemm_topk<8><<<dim3(MBLOCKS, 8), dim3(256), 0, stream>>>(zf, cbf, part);
    k_gate<8><<<dim3(M_ROWS), dim3(256), 0, stream>>>(part, target, E, out);
  } else {
    k_gemm_topk<4><<<dim3(MBLOCKS, 4), dim3(256), 0, stream>>>(zf, cbf, part);
    k_gate<4><<<dim3(M_ROWS), dim3(256), 0, stream>>>(part, target, E, out);
  }
}